// Round 5
// baseline (86.999 us; speedup 1.0000x reference)
//
#include <hip/hip_runtime.h>
#include <hip/hip_bf16.h>

// Problem constants (from reference)
#define NXD 432
#define NYD 496
#define GD  (NXD * NYD)         // 214272 (NZ = 1)
#define MAXP 100
#define MAXV 12000

// single-pass scan config
#define SCB   256               // threads per scan block
#define ITEMS 1024              // cells per scan block (4 per thread, int4)
#define NB    210               // ceil(GD / ITEMS)

// ws layout (int32 elements), all offsets even (ull-alignment for status):
//  [0] flag (1 = inputs are bf16, 0 = f32)
//  [1] nocc (total occupied voxels)
//  [8 .. 8+GD)              counts
//  [8+GD .. 8+2GD)          start   (exclusive prefix of counts)
//  [8+2GD .. 8+3GD)         cursor
//  [8+3GD .. +N)            lin per point
//  [.. +N)                  point_idx (bucketed point indices)
//  [.. +MAXV)               occ_list
//  [.. +2*NB)               status (ull[NB], decoupled-lookback)
// total ~4.2 MB

__device__ inline float bf2f(unsigned short u) {
    unsigned int x = ((unsigned int)u) << 16;
    float f;
    __builtin_memcpy(&f, &x, 4);
    return f;
}
__device__ inline unsigned short f2bf(float f) {  // round-to-nearest-even
    unsigned int x;
    __builtin_memcpy(&x, &f, 4);
    unsigned int r = (x + 0x7FFFu + ((x >> 16) & 1u)) >> 16;
    return (unsigned short)r;
}

__device__ inline unsigned long long* status_ptr(int* ws, int N) {
    return (unsigned long long*)(ws + 8 + 3 * GD + 2 * N + MAXV);
}

// Zero counts (int4/thread) + zero lookback status + detect input dtype.
// Detection: word 4i+2 as f32 is z in [-3,1] if f32 layout (100% in range);
// if bf16 layout its high half is a y-coordinate (~8% in range).
__global__ void __launch_bounds__(256) k_init(const float* inF, int* ws, int N) {
    int g = blockIdx.x * blockDim.x + threadIdx.x;
    int4* c4 = (int4*)(ws + 8);
    if (g < GD / 4) c4[g] = int4{0, 0, 0, 0};      // GD % 4 == 0
    unsigned long long* st = status_ptr(ws, N);
    if (g < NB) st[g] = 0ull;
    if (blockIdx.x == 0) {                          // block-uniform branch
        __shared__ int s_in;
        if (threadIdx.x == 0) s_in = 0;
        __syncthreads();
        const int samples = 512;
        int cnt = 0;
        for (int i = threadIdx.x; i < samples; i += blockDim.x) {
            float z = inF[4 * i + 2];
            if (z >= -3.01f && z <= 1.01f) cnt++;
        }
        atomicAdd(&s_in, cnt);
        __syncthreads();
        if (threadIdx.x == 0) ws[0] = (2 * s_in < samples) ? 1 : 0;
    }
}

__global__ void k_lin(const void* in, int* ws, int N) {
    int i = blockIdx.x * blockDim.x + threadIdx.x;
    if (i >= N) return;
    int flag = ws[0];
    float x, y, z;
    if (flag) {
        ushort4 v = ((const ushort4*)in)[i];        // 8 B vector load
        x = bf2f(v.x); y = bf2f(v.y); z = bf2f(v.z);
    } else {
        float4 v = ((const float4*)in)[i];          // 16 B vector load
        x = v.x; y = v.y; z = v.z;
    }
    // match jnp: floor((p - rmin) / vsize), f32 IEEE division (no fast-math)
    int vx = (int)floorf((x - 0.0f)   / 0.16f);
    int vy = (int)floorf((y + 39.68f) / 0.16f);
    int vz = (int)floorf((z + 3.0f)   / 4.0f);
    int l;
    if (vx >= 0 && vx < NXD && vy >= 0 && vy < NYD && vz == 0)
        l = vy * NXD + vx;
    else
        l = GD;
    int* counts = ws + 8;
    int* lin    = ws + 8 + 3 * GD;
    lin[i] = l;
    if (l < GD) atomicAdd(&counts[l], 1);
}

// Single-pass decoupled-lookback scan over GD cells of (count, occ_flag).
// Produces start[], zeroed cursor[], occ_list[], nocc in ONE dispatch.
// Status word: [63:62] flag (0=none,1=aggregate,2=prefix),
//              [41:21] occ sum, [20:0] count sum (totals < 2^21).
__global__ void __launch_bounds__(SCB) k_scan(int* ws, int N) {
    const int* counts = ws + 8;
    int* start  = ws + 8 + GD;
    int* cursor = ws + 8 + 2 * GD;
    int* occ    = ws + 8 + 3 * GD + 2 * N;
    unsigned long long* st = status_ptr(ws, N);
    __shared__ int sc[SCB], so[SCB];
    __shared__ int s_pref[2];
    int b = blockIdx.x, t = threadIdx.x;
    int base = b * ITEMS + t * 4;
    int4 c = {0, 0, 0, 0};
    if (base < GD) c = *(const int4*)(counts + base);   // GD%4==0: full or none
    int tc = c.x + c.y + c.z + c.w;
    int to = (c.x > 0) + (c.y > 0) + (c.z > 0) + (c.w > 0);
    sc[t] = tc;
    so[t] = to;
    __syncthreads();
    for (int off = 1; off < SCB; off <<= 1) {           // inclusive scan
        int a  = (t >= off) ? sc[t - off] : 0;
        int b2 = (t >= off) ? so[t - off] : 0;
        __syncthreads();
        sc[t] += a;
        so[t] += b2;
        __syncthreads();
    }
    if (t == 0) {
        unsigned long long aggc = (unsigned long long)sc[SCB - 1];
        unsigned long long aggo = (unsigned long long)so[SCB - 1];
        unsigned long long pc = 0, po = 0;
        if (b == 0) {
            __hip_atomic_store(&st[0], (2ull << 62) | (aggo << 21) | aggc,
                               __ATOMIC_RELEASE, __HIP_MEMORY_SCOPE_AGENT);
        } else {
            __hip_atomic_store(&st[b], (1ull << 62) | (aggo << 21) | aggc,
                               __ATOMIC_RELEASE, __HIP_MEMORY_SCOPE_AGENT);
            int p = b - 1;
            for (;;) {
                unsigned long long s = __hip_atomic_load(
                    &st[p], __ATOMIC_ACQUIRE, __HIP_MEMORY_SCOPE_AGENT);
                unsigned long long f = s >> 62;
                if (f == 0ull) continue;                // spin
                pc += s & 0x1FFFFFull;
                po += (s >> 21) & 0x1FFFFFull;
                if (f == 2ull) break;                   // hit a full prefix
                --p;
            }
            __hip_atomic_store(&st[b],
                               (2ull << 62) | ((aggo + po) << 21) | (aggc + pc),
                               __ATOMIC_RELEASE, __HIP_MEMORY_SCOPE_AGENT);
        }
        s_pref[0] = (int)pc;
        s_pref[1] = (int)po;
        if (b == NB - 1) ws[1] = (int)(po + aggo);      // total occupied
    }
    __syncthreads();
    if (base < GD) {
        int exc = s_pref[0] + sc[t] - tc;               // exclusive count prefix
        int exo = s_pref[1] + so[t] - to;               // exclusive occ prefix
        int4 stv;
        stv.x = exc;
        stv.y = stv.x + c.x;
        stv.z = stv.y + c.y;
        stv.w = stv.z + c.z;
        *(int4*)(start + base)  = stv;
        *(int4*)(cursor + base) = int4{0, 0, 0, 0};
        int r = exo;
        if (c.x > 0) { if (r < MAXV) occ[r] = base;     r++; }
        if (c.y > 0) { if (r < MAXV) occ[r] = base + 1; r++; }
        if (c.z > 0) { if (r < MAXV) occ[r] = base + 2; r++; }
        if (c.w > 0) { if (r < MAXV) occ[r] = base + 3; r++; }
    }
}

__global__ void k_place(int* ws, int N) {
    int i = blockIdx.x * blockDim.x + threadIdx.x;
    if (i >= N) return;
    const int* start  = ws + 8 + GD;
    int* cursor = ws + 8 + 2 * GD;
    const int* lin = ws + 8 + 3 * GD;
    int* pidx = ws + 8 + 3 * GD + N;
    int l = lin[i];
    if (l < GD) {
        int pos = start[l] + atomicAdd(&cursor[l], 1);
        pidx[pos] = i;
    }
}

// One block per output voxel slot. Sorts the voxel's point indices ascending
// (reproducing stable-argsort slot order), then one thread per point slot
// moves a whole point as float4 (f32) / ushort4 (bf16). Covers every output
// element each call (repaints poison).
__global__ void k_out(const void* in, const int* ws, void* out, int N) {
    __shared__ int idxs[MAXP];
    __shared__ int sv, scnt, sst;
    int s = blockIdx.x;
    int t = threadIdx.x;
    int flag = ws[0];
    int nocc = ws[1];
    const int* counts = ws + 8;
    const int* start  = ws + 8 + GD;
    const int* pidx   = ws + 8 + 3 * GD + N;
    const int* occ    = pidx + N;

    bool pad = (s >= nocc);
    int v = 0, cnt = 0, c = 0;
    if (!pad) {  // block-uniform branch: barriers are safe
        if (t == 0) {
            sv = occ[s];
            scnt = counts[sv];
            sst = start[sv];
        }
        __syncthreads();
        v = sv;
        cnt = scnt;
        c = min(cnt, MAXP);
        for (int k = t; k < c; k += blockDim.x) idxs[k] = pidx[sst + k];
        __syncthreads();
        if (t == 0) {  // insertion sort (c is ~<=10 for this input)
            for (int a = 1; a < c; a++) {
                int key = idxs[a];
                int b = a - 1;
                while (b >= 0 && idxs[b] > key) { idxs[b + 1] = idxs[b]; b--; }
                idxs[b + 1] = key;
            }
        }
        __syncthreads();
    }

    const size_t VOXN = (size_t)MAXV * MAXP * 4;   // 4,800,000 elements
    const size_t CO   = VOXN;                      // coords base
    const size_t NU   = VOXN + (size_t)MAXV * 3;   // num_points base

    int zc = 0, yc = 0, xc = 0;
    if (!pad) {
        zc = 0;                // NZ = 1
        yc = v / NXD;
        xc = v % NXD;
    }

    if (flag) {
        unsigned short* o = (unsigned short*)out;
        const ushort4* p4 = (const ushort4*)in;
        if (t < MAXP) {
            ushort4 val = {0, 0, 0, 0};
            if (!pad && t < c) val = p4[idxs[t]];          // exact bit copy
            ((ushort4*)o)[(size_t)s * MAXP + t] = val;
        }
        if (t < 4) {
            int val;
            size_t off;
            if (t < 3) {
                val = pad ? -1 : (t == 0 ? zc : (t == 1 ? yc : xc));
                off = CO + (size_t)s * 3 + t;
            } else {
                val = pad ? 0 : cnt;
                off = NU + s;
            }
            o[off] = f2bf((float)val);
        }
    } else {
        float* o = (float*)out;
        const float4* p4 = (const float4*)in;
        if (t < MAXP) {
            float4 val = {0.0f, 0.0f, 0.0f, 0.0f};
            if (!pad && t < c) val = p4[idxs[t]];          // exact bit copy
            ((float4*)o)[(size_t)s * MAXP + t] = val;
        }
        if (t < 4) {
            int val;
            size_t off;
            if (t < 3) {
                val = pad ? -1 : (t == 0 ? zc : (t == 1 ? yc : xc));
                off = CO + (size_t)s * 3 + t;
            } else {
                val = pad ? 0 : cnt;
                off = NU + s;
            }
            o[off] = (float)val;
        }
    }
}

extern "C" void kernel_launch(void* const* d_in, const int* in_sizes, int n_in,
                              void* d_out, int out_size, void* d_ws, size_t ws_size,
                              hipStream_t stream) {
    const void* in = d_in[0];
    int N = in_sizes[0] / 4;   // 200000 points x 4 components
    int* ws = (int*)d_ws;

    k_init<<<NB, 256, 0, stream>>>((const float*)in, ws, N);
    k_lin<<<(N + 255) / 256, 256, 0, stream>>>(in, ws, N);
    k_scan<<<NB, SCB, 0, stream>>>(ws, N);
    k_place<<<(N + 255) / 256, 256, 0, stream>>>(ws, N);
    k_out<<<MAXV, 128, 0, stream>>>(in, ws, d_out, N);
}